// Round 14
// baseline (514.297 us; speedup 1.0000x reference)
//
#include <hip/hip_runtime.h>
#include <math.h>

// ---------------------------------------------------------------------------
// TbDNet forward, round 14: round-13 structure + coalesced stem1 input path:
//  - k_tr: feats [n][ic][px] f32 -> FT [n][px][ic] bf16 (LDS tile transpose)
//  - k_stem1p: straight short8 staging from FT (coalesced), 8 K-splits
// ---------------------------------------------------------------------------

typedef __attribute__((ext_vector_type(8)))  short   short8;
typedef __attribute__((ext_vector_type(8)))  __bf16  bf16x8;
typedef __attribute__((ext_vector_type(4)))  float   f32x4;

#define NROUNDS 8
#define NKS 98          // fc1 K-splits (KC = 512)
#define S1KS 8          // stem1 K-splits (128 ic each)

// byte offsets in ws
#define B_WSTEM1 0UL                 // bf16 [9][128][1024]
#define B_WSTEM2 2359296UL           // bf16 [9][128][128]
#define B_WMOD   2654208UL           // 9 x bf16 [9][128][128]
#define B_WCLS   5308416UL           // bf16 [1024][128]
#define B_STEM   5570560UL           // bf16 [64][196][128]
#define B_XA     8781824UL
#define B_XB     11993088UL
#define B_FEAT   15204352UL
#define B_ATTN   18415616UL          // f32 [64][196]
#define B_SAVED  18465792UL
#define B_SCHED  18515968UL          // int [64][NROUNDS]
#define B_ACTB   18520064UL          // bf16 permuted fc1-B
#define B_FC1T   24942592UL          // f32 [1024][64]
#define B_P1X1   25204736UL          // f32 [8 slots][64][196]
#define B_FT     33554432UL          // bf16 [64][196][1024] = 25.7 MB
// high overlays (ws ~800 MB):
#define B_S1P    67108864UL          // stem1 partials bf16 [8][64][196][128]
#define B_FC1P   134217728UL         // fc1 partials f32 [98][1024][64]

__device__ __forceinline__ unsigned short f2bf(float f) {
    __bf16 h = (__bf16)f;
    union { __bf16 h; unsigned short u; } c; c.h = h; return c.u;
}
__device__ __forceinline__ float bf2f(unsigned short u) {
    return __uint_as_float(((unsigned int)u) << 16);
}
__device__ __forceinline__ unsigned int pkbf(float a, float b) {
    return (unsigned int)f2bf(a) | ((unsigned int)f2bf(b) << 16);
}
__device__ __forceinline__ f32x4 mfma16(bf16x8 a, bf16x8 b, f32x4 c) {
    return __builtin_amdgcn_mfma_f32_16x16x32_bf16(a, b, c, 0, 0, 0);
}

// ---------------------------------------------------------------------------
// k_tr: transpose+convert feats -> FT bf16 [n][196][1024].
// Block = (n, it 0..31): 32-ic x 196-px tile via LDS [32][201] f32.
// ---------------------------------------------------------------------------
__global__ __launch_bounds__(256) void k_tr(const float* __restrict__ feats,
                                            unsigned short* __restrict__ ft)
{
    __shared__ float s[32 * 201];
    const int n = blockIdx.x >> 5, it = blockIdx.x & 31;
    const int tid = threadIdx.x, lane = tid & 63, w = tid >> 6;
    const float* src = feats + ((size_t)n * 1024 + it * 32) * 196;

    for (int r = w; r < 32; r += 4) {
        if (lane < 49) {
            float4 v = *(const float4*)(src + r * 196 + lane * 4);
            float* sr = s + r * 201 + lane * 4;
            sr[0] = v.x; sr[1] = v.y; sr[2] = v.z; sr[3] = v.w;
        }
    }
    __syncthreads();

    const int ic4 = (tid & 7) * 4;
    unsigned short* dst = ft + (size_t)n * 200704 + it * 32 + ic4;
    for (int p = tid >> 3; p < 196; p += 32) {
        uint2 v;
        v.x = pkbf(s[(ic4 + 0) * 201 + p], s[(ic4 + 1) * 201 + p]);
        v.y = pkbf(s[(ic4 + 2) * 201 + p], s[(ic4 + 3) * 201 + p]);
        *(uint2*)(dst + (size_t)p * 1024) = v;
    }
}

// ---------------------------------------------------------------------------
// k_prep: weight repack (blocks 0..767) + program decode/state init (768..1023)
// ---------------------------------------------------------------------------
struct PrepArgs { const float* src[12]; const int* prog; char* ws; };

__global__ __launch_bounds__(256) void k_prep(PrepArgs a)
{
    char* ws = a.ws;
    const int bx = blockIdx.x;
    if (bx < 768) {
        const int y = bx >> 6;
        const float* __restrict__ src = a.src[y];
        int gid = (bx & 63) * 256 + threadIdx.x;
        int gsz = 64 * 256;
        if (y == 11) {
            unsigned short* dst = (unsigned short*)(ws + B_WCLS);
            for (int i = gid; i < 131072; i += gsz) dst[i] = f2bf(src[i]);
        } else {
            const int IC = (y == 0) ? 1024 : 128;
            const int lg = (y == 0) ? 10 : 7;
            unsigned short* dst = (unsigned short*)(ws + ((y == 0) ? B_WSTEM1
                                        : (y == 1) ? B_WSTEM2
                                        : B_WMOD + (size_t)(y - 2) * 294912));
            const int total = 9 << (lg + 7);
            for (int i = gid; i < total; i += gsz) {
                int ic = i & (IC - 1);
                int oc = (i >> lg) & 127;
                int t  = i >> (lg + 7);
                dst[i] = f2bf(src[((size_t)oc * IC + ic) * 9 + t]);
            }
        }
        return;
    }
    int gid = (bx - 768) * 256 + threadIdx.x;
    int gsz = 256 * 256;
    float* attn  = (float*)(ws + B_ATTN);
    float* saved = (float*)(ws + B_SAVED);
    float* p1    = (float*)(ws + B_P1X1);
    for (int i = gid; i < 64 * 196; i += gsz) { attn[i] = 1.0f; saved[i] = 1.0f; }
    for (int i = gid; i < 8 * 64 * 196; i += gsz) p1[i] = 0.0f;
    unsigned int* fz = (unsigned int*)(ws + B_FEAT);
    for (int i = gid; i < 64 * 25088 / 2; i += gsz) fz[i] = 0u;
    if (gid < 64) {
        int n = gid;
        const int* prog = a.prog;
        int ent[NROUNDS];
        for (int r = 0; r < NROUNDS; ++r) ent[r] = 0;
        int rc = 0, nslot = 0;
        int pscene = 0, pinter = 0, pmat = 0, pmw = 0;
#define PREBITS ((pscene<<17)|(pinter<<18)|(pmat<<19)|(pmw<<22))
#define CLRPRE  (pscene = pinter = pmat = pmw = 0)
#define EMIT(v) do { if (rc < NROUNDS) ent[rc++] = (v); } while (0)
        for (int j = 7; j >= 0; --j) {
            int t = prog[n * 8 + j];
            switch (t) {
                case 3: pscene = 1; break;               // SCENE
                case 4: pinter = 1; break;               // INTERSECT
                case 5: {                                 // FILT -> fused
                    int e1 = 5 | (0<<4) | (1<<8) | (1<<12) | (0<<15) | PREBITS
                               | (1<<23) | (0<<24) | (nslot<<25);
                    CLRPRE; EMIT(e1);
                    pmat = nslot + 1; pmw = 0; nslot++;
                    break;
                }
                case 6: {                                 // RELATE -> 5 plain
                    int e1 = 3 | (2<<4) | (1<<8) | (1<<12) | (2<<13) | (0<<15) | PREBITS;
                    CLRPRE; EMIT(e1);
                    EMIT(3 | (3<<4) | (2<<8) | (0<<13) | (1<<15));
                    EMIT(3 | (4<<4) | (4<<8) | (1<<13) | (0<<15));
                    EMIT(3 | (5<<4) | (8<<8) | (0<<13) | (1<<15));
                    EMIT(3 | (6<<4) | (1<<8) | (1<<13) | (0<<15)
                           | (1<<23) | (1<<24) | (nslot<<25));
                    pmat = nslot + 1; pmw = 1; nslot++;
                    break;
                }
                case 7: {                                 // QUERY -> fused
                    int e1 = 5 | (7<<4) | (8<<8) | (1<<12) | (2<<15) | PREBITS;
                    CLRPRE; EMIT(e1);
                    break;
                }
                default: break;
            }
        }
#undef EMIT
#undef PREBITS
#undef CLRPRE
        int* sched = (int*)(ws + B_SCHED);
        for (int r = 0; r < NROUNDS; ++r) sched[n * NROUNDS + r] = ent[r];
    }
}

// ---------------------------------------------------------------------------
// stem1 partial conv: block = (n, ks 0..7), 512 threads, 128-ic slab from FT.
// Staging is a straight coalesced short8 copy (FT is [px][1024] bf16).
// ---------------------------------------------------------------------------
__global__ __launch_bounds__(512) void k_stem1p(const unsigned short* __restrict__ ft,
                                                const unsigned short* __restrict__ wrep,
                                                char* ws)
{
    __shared__ unsigned short s_img[197 * 136];
    const int bx = blockIdx.x;
    const int n = bx >> 3, ks = bx & 7;
    const int tid = threadIdx.x, lane = tid & 63;
    const int w = tid >> 6, wm = w & 1, wn = w >> 1;
    const int l15 = lane & 15, lq = lane >> 4;
    const int icb = ks * 128;

    if (tid < 68) ((unsigned int*)s_img)[196 * 68 + tid] = 0u;   // zero row

    const unsigned short* slab = ft + (size_t)n * 200704 + icb;
    for (int i = tid; i < 196 * 16; i += 512) {
        int p = i >> 4, c8 = (i & 15) * 8;
        *(short8*)(s_img + p * 136 + c8) = *(const short8*)(slab + (size_t)p * 1024 + c8);
    }

    int pglob[4], pbyt[4], pyv[4], pxv[4];
#pragma unroll
    for (int j = 0; j < 4; ++j) {
        int p  = (wn + 4 * j) * 16 + l15;
        pglob[j] = p;
        int py = p / 14;
        pyv[j] = (p < 196) ? py : 10000;
        pxv[j] = p - py * 14;
        pbyt[j] = p * 272 + lq * 16;
    }
    const int zaddr = 196 * 272 + lq * 16;
    const int nJ = (wn == 0) ? 4 : 3;

    f32x4 acc[4][4];
#pragma unroll
    for (int m = 0; m < 4; ++m)
#pragma unroll
        for (int j = 0; j < 4; ++j) acc[m][j] = (f32x4){0.f, 0.f, 0.f, 0.f};
    __syncthreads();

#pragma unroll
    for (int t = 0; t < 9; ++t) {
        const int dy = t / 3 - 1, dx = t % 3 - 1;
        int baddr[4];
#pragma unroll
        for (int j = 0; j < 4; ++j) {
            int yy = pyv[j] + dy, xx = pxv[j] + dx;
            bool ok = ((unsigned)yy < 14u) && ((unsigned)xx < 14u);
            baddr[j] = ok ? (pbyt[j] + (dy * 14 + dx) * 272) : zaddr;
        }
#pragma unroll
        for (int kc = 0; kc < 4; ++kc) {
            const unsigned short* wt = wrep +
                ((size_t)(t * 128 + wm * 64 + l15) * 1024 + icb + kc * 32 + lq * 8);
            bf16x8 am[4];
#pragma unroll
            for (int m = 0; m < 4; ++m)
                am[m] = *(const bf16x8*)(wt + (size_t)m * 16 * 1024);
#pragma unroll
            for (int j = 0; j < 4; ++j) {
                if (j < nJ) {
                    bf16x8 b = *(const bf16x8*)((const char*)s_img + baddr[j] + kc * 64);
#pragma unroll
                    for (int m = 0; m < 4; ++m)
                        acc[m][j] = mfma16(am[m], b, acc[m][j]);
                }
            }
        }
    }

    unsigned short* part = (unsigned short*)(ws + B_S1P);
#pragma unroll
    for (int m = 0; m < 4; ++m) {
        const int oc = wm * 64 + m * 16 + lq * 4;
#pragma unroll
        for (int j = 0; j < 4; ++j) {
            if (j < nJ) {
                int p = pglob[j];
                if (p < 196) {
                    uint2 pk;
                    pk.x = pkbf(acc[m][j][0], acc[m][j][1]);
                    pk.y = pkbf(acc[m][j][2], acc[m][j][3]);
                    *(uint2*)(part + (((size_t)ks * 64 + n) * 196 + p) * 128 + oc) = pk;
                }
            }
        }
    }
}

// stem1 reduce: sum 8 bf16 partials + bias + relu -> XA bf16 [n][p][128]
__global__ __launch_bounds__(256) void k_stem1r(const char* __restrict__ ws_c,
                                                const float* __restrict__ bias,
                                                unsigned short* __restrict__ xa)
{
    int i = blockIdx.x * 256 + threadIdx.x;
    const unsigned short* part = (const unsigned short*)(ws_c + B_S1P);
    int oc8 = (i & 15) * 8;
    int np  = i >> 4;
    float s[8] = {};
#pragma unroll
    for (int ks = 0; ks < S1KS; ++ks) {
        short8 v = *(const short8*)(part + (((size_t)ks * 64) * 196 + np) * 128 + oc8);
#pragma unroll
        for (int e = 0; e < 8; ++e) s[e] += bf2f((unsigned short)v[e]);
    }
    short8 o;
#pragma unroll
    for (int e = 0; e < 8; ++e)
        o[e] = (short)f2bf(fmaxf(s[e] + bias[oc8 + e], 0.f));
    *(short8*)(xa + (size_t)np * 128 + oc8) = o;
}

// ---------------------------------------------------------------------------
// MFMA 3x3 conv core, 32-oc tile, 256-thr (stem2 only).
// ---------------------------------------------------------------------------
__device__ void conv_core32(const unsigned short* __restrict__ srcB,
                            const unsigned short* __restrict__ wrep,
                            const float* __restrict__ bias,
                            unsigned short* __restrict__ dst,
                            int oct, int pxh,
                            unsigned short* s_img)
{
    const int tid  = threadIdx.x, lane = tid & 63;
    const int w    = tid >> 6, wm = w & 1, wn = w >> 1;
    const int l15  = lane & 15, lq = lane >> 4;

    if (tid < 68) ((unsigned int*)s_img)[196 * 68 + tid] = 0u;

    int pglob[4], pbyt[4], pyv[4], pxv[4];
#pragma unroll
    for (int j = 0; j < 4; ++j) {
        int nt = wn + 2 * j;
        int p  = (pxh * 7 + nt) * 16 + l15;
        pglob[j] = p;
        int py = p / 14;
        pyv[j] = (p < 196) ? py : 10000;
        pxv[j] = p - py * 14;
        pbyt[j] = p * 272 + lq * 16;
    }
    const int zaddr = 196 * 272 + lq * 16;
    const int nNT = (wn == 0) ? 4 : 3;

    f32x4 acc[4];
#pragma unroll
    for (int j = 0; j < 4; ++j) acc[j] = (f32x4){0.f, 0.f, 0.f, 0.f};

    for (int i = tid; i < 196 * 16; i += 256) {
        int p = i >> 4, c8 = (i & 15) * 8;
        *(short8*)(s_img + p * 136 + c8) = *(const short8*)(srcB + p * 128 + c8);
    }
    __syncthreads();

    const unsigned short* wlane = wrep + (size_t)(oct * 32 + wm * 16 + l15) * 128 + lq * 8;
#pragma unroll
    for (int t = 0; t < 9; ++t) {
        const int dy = t / 3 - 1, dx = t % 3 - 1;
        int baddr[4];
#pragma unroll
        for (int j = 0; j < 4; ++j) {
            int yy = pyv[j] + dy, xx = pxv[j] + dx;
            bool ok = ((unsigned)yy < 14u) && ((unsigned)xx < 14u);
            baddr[j] = ok ? (pbyt[j] + (dy * 14 + dx) * 272) : zaddr;
        }
        const unsigned short* wt = wlane + (size_t)(t * 128) * 128;
#pragma unroll
        for (int kc = 0; kc < 4; ++kc) {
            bf16x8 a0 = *(const bf16x8*)(wt + kc * 32);
#pragma unroll
            for (int j = 0; j < 4; ++j) {
                if (j < nNT) {
                    bf16x8 b = *(const bf16x8*)((const char*)s_img + baddr[j] + kc * 64);
                    acc[j] = mfma16(a0, b, acc[j]);
                }
            }
        }
    }

    const int oc = oct * 32 + wm * 16 + lq * 4;
    const float4 b4 = *(const float4*)(bias + oc);
#pragma unroll
    for (int j = 0; j < 4; ++j) {
        if (j < nNT) {
            int p = pglob[j];
            if (p < 196) {
                uint2 pk;
                pk.x = pkbf(fmaxf(acc[j][0] + b4.x, 0.f), fmaxf(acc[j][1] + b4.y, 0.f));
                pk.y = pkbf(fmaxf(acc[j][2] + b4.z, 0.f), fmaxf(acc[j][3] + b4.w, 0.f));
                *(uint2*)(dst + p * 128 + oc) = pk;
            }
        }
    }
}

__global__ __launch_bounds__(256) void k_conv_stem2(const unsigned short* __restrict__ srcBall,
                                                    const unsigned short* __restrict__ wrep,
                                                    const float* __restrict__ bias,
                                                    unsigned short* __restrict__ dstall)
{
    __shared__ unsigned short s_img[197 * 136];
    const int n = blockIdx.x >> 3, oct = (blockIdx.x >> 1) & 3, pxh = blockIdx.x & 1;
    conv_core32(srcBall + (size_t)n * 25088, wrep, bias,
                dstall + (size_t)n * 25088, oct, pxh, s_img);
}

// ---------------------------------------------------------------------------
// Module interpreter round: 256 blocks = (n, oct), 512 threads (round-13).
// ---------------------------------------------------------------------------
struct RArgs {
    char* ws;
    const float* mbias[9];
    const float* w1x1[2];
    const float* b1x1[2];
};

__global__ __launch_bounds__(512) void k_round(RArgs a, int r)
{
    __shared__ unsigned short s_img[197 * 136];
    __shared__ unsigned short s_tmp[197 * 136];
    __shared__ float s_gate[196];
    const int bx = blockIdx.x;
    const int n = bx >> 2, oct = bx & 3;
    char* ws = a.ws;
    const int* sched = (const int*)(ws + B_SCHED);
    const int e = sched[n * NROUNDS + r];
    const int op = e & 15;
    if (op == 0) return;
    const int tid = threadIdx.x, lane = tid & 63;
    const int w = tid >> 6, wm = w & 1, wn = w >> 1;
    const int l15 = lane & 15, lq = lane >> 4;
    const int wset1 = (e >> 4) & 15, f8 = (e >> 8) & 15, gatef = (e >> 12) & 1;
    const int srcid = (e >> 13) & 3, dstid = (e >> 15) & 3;
    const int fscene = (e >> 17) & 1, finter = (e >> 18) & 1;
    const int mslot = (e >> 19) & 7, mw = (e >> 22) & 1;
    const int post = (e >> 23) & 1, pw = (e >> 24) & 1, pslot = (e >> 25) & 7;

    float* attn  = (float*)(ws + B_ATTN)  + n * 196;
    float* saved = (float*)(ws + B_SAVED) + n * 196;
    float* p1    = (float*)(ws + B_P1X1);

    if (tid < 68) ((unsigned int*)s_img)[196 * 68 + tid] = 0u;
    else if (tid < 136) ((unsigned int*)s_tmp)[196 * 68 + (tid - 68)] = 0u;

    if (gatef && tid < 196) {
        float cur = attn[tid];
        if (mslot) {
            float pv = p1[(size_t)(mslot - 1) * 12544 + n * 196 + tid];
            cur = 1.0f / (1.0f + __expf(-(pv + a.b1x1[mw][0])));
        }
        if (fscene) { saved[tid] = cur; cur = 1.0f; }
        if (finter) { cur = fminf(cur, saved[tid]); }
        if (mslot | fscene | finter) attn[tid] = cur;
        s_gate[tid] = cur;
    }
    __syncthreads();

    const int zaddr = 196 * 272 + lq * 16;
    const unsigned short* wmod = (const unsigned short*)(ws + B_WMOD);

    if (op == 3) {
        // ---------------- plain conv, full px, dil = f8 ----------------
        const unsigned short* src = (const unsigned short*)(ws +
                (srcid == 2 ? B_STEM : srcid == 1 ? B_XB : B_XA)) + (size_t)n * 25088;
        if (gatef) {
            for (int i = tid; i < 196 * 16; i += 512) {
                int p = i >> 4, c8 = (i & 15) * 8;
                short8 v = *(const short8*)(src + p * 128 + c8);
                float g = s_gate[p];
                uint2 o0, o1;
                o0.x = pkbf(bf2f((unsigned short)v[0]) * g, bf2f((unsigned short)v[1]) * g);
                o0.y = pkbf(bf2f((unsigned short)v[2]) * g, bf2f((unsigned short)v[3]) * g);
                o1.x = pkbf(bf2f((unsigned short)v[4]) * g, bf2f((unsigned short)v[5]) * g);
                o1.y = pkbf(bf2f((unsigned short)v[6]) * g, bf2f((unsigned short)v[7]) * g);
                *(uint2*)(s_img + p * 136 + c8)     = o0;
                *(uint2*)(s_img + p * 136 + c8 + 4) = o1;
            }
        } else {
            for (int i = tid; i < 196 * 16; i += 512) {
                int p = i >> 4, c8 = (i & 15) * 8;
                *(short8*)(s_img + p * 136 + c8) = *(const short8*)(src + p * 128 + c8);
            }
        }
        __syncthreads();

        int pglob[4], pbyt[4], pyv[4], pxv[4];
#pragma unroll
        for (int j = 0; j < 4; ++j) {
            int p = (wn + 4 * j) * 16 + l15;
            pglob[j] = p;
            int py = p / 14;
            pyv[j] = (p < 196) ? py : 10000;
            pxv[j] = p - py * 14;
            pbyt[j] = p * 272 + lq * 16;
        }
        const int nJ = (wn == 0) ? 4 : 3;
        f32x4 acc[4];
#pragma unroll
        for (int j = 0; j < 4; ++j) acc[j] = (f32x4){0.f, 0.f, 0.f, 0.f};

        const int dil = f8;
        const unsigned short* wlane = wmod + (size_t)wset1 * 9 * 128 * 128
                     + (size_t)(oct * 32 + wm * 16 + l15) * 128 + lq * 8;
#pragma unroll
        for (int t = 0; t < 9; ++t) {
            const int dy = (t / 3 - 1) * dil, dx = (t % 3 - 1) * dil;
            int ba[4];
#pragma unroll
            for (int j = 0; j < 4; ++j) {
                int yy = pyv[j] + dy, xx = pxv[j] + dx;
                bool ok = ((unsigned)yy < 14u) && ((unsigned)xx < 14u);
                ba[j] = ok ? (pbyt[j] + (dy * 14 + dx) * 272) : zaddr;
            }
            const unsigned short* wt = wlane + (size_t)(t * 128) * 128;
#pragma unroll
            for (int kc = 0; kc < 4; ++kc) {
                bf16x8 a0 = *(const bf16x8*)(wt + kc * 32);
#pragma unroll
                for (int j = 0; j < 4; ++j) {
                    if (j < nJ) {
                        bf16x8 b = *(const bf16x8*)((const char*)s_img + ba[j] + kc * 64);
                        acc[j] = mfma16(a0, b, acc[j]);
                    }
                }
            }
        }

        unsigned short* dst = (unsigned short*)(ws +
                (dstid == 2 ? B_FEAT : dstid == 1 ? B_XB : B_XA)) + (size_t)n * 25088;
        const int oc = oct * 32 + wm * 16 + lq * 4;
        const float4 b4 = *(const float4*)(a.mbias[wset1] + oc);
        float4 wv4;
        if (post) wv4 = *(const float4*)(a.w1x1[pw] + oc);
        float* pdst = p1 + (size_t)pslot * 12544 + n * 196;
#pragma unroll
        for (int j = 0; j < 4; ++j) {
            if (j < nJ) {
                int p = pglob[j];
                if (p < 196) {
                    float v0 = fmaxf(acc[j][0] + b4.x, 0.f);
                    float v1 = fmaxf(acc[j][1] + b4.y, 0.f);
                    float v2 = fmaxf(acc[j][2] + b4.z, 0.f);
                    float v3 = fmaxf(acc[j][3] + b4.w, 0.f);
                    uint2 pk; pk.x = pkbf(v0, v1); pk.y = pkbf(v2, v3);
                    *(uint2*)(dst + p * 128 + oc) = pk;
                    if (post)
                        atomicAdd(pdst + p, v0 * wv4.x + v1 * wv4.y + v2 * wv4.z + v3 * wv4.w);
                }
            }
        }
    } else {
        // ---------------- fused 2-conv (dil=1): conv1 full -> conv2 slice ----
        const unsigned short* stem = (const unsigned short*)(ws + B_STEM) + (size_t)n * 25088;
        for (int i = tid; i < 196 * 16; i += 512) {
            int p = i >> 4, c8 = (i & 15) * 8;
            short8 v = *(const short8*)(stem + p * 128 + c8);
            float g = s_gate[p];
            uint2 o0, o1;
            o0.x = pkbf(bf2f((unsigned short)v[0]) * g, bf2f((unsigned short)v[1]) * g);
            o0.y = pkbf(bf2f((unsigned short)v[2]) * g, bf2f((unsigned short)v[3]) * g);
            o1.x = pkbf(bf2f((unsigned short)v[4]) * g, bf2f((unsigned short)v[5]) * g);
            o1.y = pkbf(bf2f((unsigned short)v[6]) * g, bf2f((unsigned short)v[7]) * g);
            *(uint2*)(s_img + p * 136 + c8)     = o0;
            *(uint2*)(s_img + p * 136 + c8 + 4) = o1;
        }
        __syncthreads();

        const unsigned short* w1 = wmod + (size_t)wset1 * 9 * 128 * 128;
        int pg2[13], pb2[13], pyv2[13], pxv2[13];
#pragma unroll
        for (int j2 = 0; j2 < 13; ++j2) {
            int p = j2 * 16 + l15;
            pg2[j2] = p;
            int py = p / 14;
            pyv2[j2] = (p < 196) ? py : 10000;
            pxv2[j2] = p - py * 14;
            pb2[j2] = p * 272 + lq * 16;
        }
        f32x4 acc1[13];
#pragma unroll
        for (int j2 = 0; j2 < 13; ++j2) acc1[j2] = (f32x4){0.f, 0.f, 0.f, 0.f};
#pragma unroll
        for (int t = 0; t < 9; ++t) {
            const int dy = t / 3 - 1, dx = t % 3 - 1;
            int ba[13];
#pragma unroll
            for (int j2 = 0; j2 < 13; ++j2) {
                int yy = pyv2[j2] + dy, xx = pxv2[j2] + dx;
                bool ok = ((unsigned)yy < 14u) && ((unsigned)xx < 14u);
                ba[j2] = ok ? (pb2[j2] + (dy * 14 + dx) * 272) : zaddr;
            }
#pragma unroll
            for (int kc = 0; kc < 4; ++kc) {
                bf16x8 av = *(const bf16x8*)(w1 +
                    (size_t)(t * 128 + w * 16 + l15) * 128 + kc * 32 + lq * 8);
#pragma unroll
                for (int j2 = 0; j2 < 13; ++j2) {
                    bf16x8 b = *(const bf16x8*)((const char*)s_img + ba[j2] + kc * 64);
                    acc1[j2] = mfma16(av, b, acc1[j2]);
                }
            }
        }
        {
            const int oc1 = w * 16 + lq * 4;
            const float4 b14 = *(const float4*)(a.mbias[wset1] + oc1);
#pragma unroll
            for (int j2 = 0; j2 < 13; ++j2) {
                int p = pg2[j2];
                if (p < 196) {
                    uint2 pk;
                    pk.x = pkbf(fmaxf(acc1[j2][0] + b14.x, 0.f),
                                fmaxf(acc1[j2][1] + b14.y, 0.f));
                    pk.y = pkbf(fmaxf(acc1[j2][2] + b14.z, 0.f),
                                fmaxf(acc1[j2][3] + b14.w, 0.f));
                    *(uint2*)(s_tmp + p * 136 + oc1) = pk;
                }
            }
        }
        __syncthreads();

        const unsigned short* w2base = wmod + (size_t)f8 * 9 * 128 * 128
                     + (size_t)(oct * 32 + wm * 16 + l15) * 128 + lq * 8;
        int pglob[4], pbyt[4], pyv[4], pxv[4];
#pragma unroll
        for (int j = 0; j < 4; ++j) {
            int p = (wn + 4 * j) * 16 + l15;
            pglob[j] = p;
            int py = p / 14;
            pyv[j] = (p < 196) ? py : 10000;
            pxv[j] = p - py * 14;
            pbyt[j] = p * 272 + lq * 16;
        }
        const int nJ = (wn == 0) ? 4 : 3;
        f32x4 acc[4];
#pragma unroll
        for (int j = 0; j < 4; ++j) acc[j] = (f32x4){0.f, 0.f, 0.f, 0.f};
#pragma unroll
        for (int t = 0; t < 9; ++t) {
            const int dy = t / 3 - 1, dx = t % 3 - 1;
            int ba[4];
#pragma unroll
            for (int j = 0; j < 4; ++j) {
                int yy = pyv[j] + dy, xx = pxv[j] + dx;
                bool ok = ((unsigned)yy < 14u) && ((unsigned)xx < 14u);
                ba[j] = ok ? (pbyt[j] + (dy * 14 + dx) * 272) : zaddr;
            }
            const unsigned short* wt = w2base + (size_t)(t * 128) * 128;
#pragma unroll
            for (int kc = 0; kc < 4; ++kc) {
                bf16x8 a0 = *(const bf16x8*)(wt + kc * 32);
#pragma unroll
                for (int j = 0; j < 4; ++j) {
                    if (j < nJ) {
                        bf16x8 b = *(const bf16x8*)((const char*)s_tmp + ba[j] + kc * 64);
                        acc[j] = mfma16(a0, b, acc[j]);
                    }
                }
            }
        }
        const int oc = oct * 32 + wm * 16 + lq * 4;
        const float4 b24 = *(const float4*)(a.mbias[f8] + oc);
        unsigned short* feat = (unsigned short*)(ws + B_FEAT) + (size_t)n * 25088;
        float4 wv4;
        if (post) wv4 = *(const float4*)(a.w1x1[pw] + oc);
        float* pdst = p1 + (size_t)pslot * 12544 + n * 196;
#pragma unroll
        for (int j = 0; j < 4; ++j) {
            if (j < nJ) {
                int p = pglob[j];
                if (p < 196) {
                    float v0 = fmaxf(acc[j][0] + b24.x, 0.f);
                    float v1 = fmaxf(acc[j][1] + b24.y, 0.f);
                    float v2 = fmaxf(acc[j][2] + b24.z, 0.f);
                    float v3 = fmaxf(acc[j][3] + b24.w, 0.f);
                    if (dstid == 2) {
                        uint2 pk; pk.x = pkbf(v0, v1); pk.y = pkbf(v2, v3);
                        *(uint2*)(feat + p * 128 + oc) = pk;
                    }
                    if (post)
                        atomicAdd(pdst + p, v0 * wv4.x + v1 * wv4.y + v2 * wv4.z + v3 * wv4.w);
                }
            }
        }
    }
}

// ---------------------------------------------------------------------------
// cls 1x1 conv (128->1024, MFMA) + bias + relu + 2x2 maxpool -> actB bf16
// ---------------------------------------------------------------------------
__global__ __launch_bounds__(256) void k_cls_pool(const unsigned short* __restrict__ featall,
                                                  const unsigned short* __restrict__ clsw,
                                                  const float* __restrict__ clsb,
                                                  unsigned short* __restrict__ actB)
{
    __shared__ char smem[197 * 272 + 64 * 200 * 4];
    unsigned short* s_img = (unsigned short*)smem;
    float* s_pool = (float*)(smem + 197 * 272);
    const int n = blockIdx.x >> 4, pt = blockIdx.x & 15;
    const int tid = threadIdx.x, lane = tid & 63, w = tid >> 6;
    const int l15 = lane & 15, lq = lane >> 4;
    const unsigned short* feat = featall + (size_t)n * 25088;

    if (tid < 68) ((unsigned int*)s_img)[196 * 68 + tid] = 0u;
    for (int i = tid; i < 196 * 16; i += 256) {
        int p = i >> 4, c8 = (i & 15) * 8;
        *(short8*)(s_img + p * 136 + c8) = *(const short8*)(feat + p * 128 + c8);
    }
    f32x4 acc[14];
#pragma unroll
    for (int j = 0; j < 14; ++j) acc[j] = (f32x4){0.f, 0.f, 0.f, 0.f};
    __syncthreads();

    const unsigned short* wl = clsw + (size_t)(pt * 64 + w * 16 + l15) * 128 + lq * 8;
#pragma unroll
    for (int kc = 0; kc < 4; ++kc) {
        bf16x8 a0 = *(const bf16x8*)(wl + kc * 32);
#pragma unroll
        for (int j = 0; j < 14; ++j) {
            int p = j * 16 + l15;
            int ba = (p < 196) ? (p * 272 + lq * 16 + kc * 64) : (196 * 272 + lq * 16);
            bf16x8 b = *(const bf16x8*)((const char*)s_img + ba);
            acc[j] = mfma16(a0, b, acc[j]);
        }
    }
    const int oc = pt * 64 + w * 16 + lq * 4;
    const float4 b4 = *(const float4*)(clsb + oc);
    const int pl = w * 16 + lq * 4;
#pragma unroll
    for (int j = 0; j < 14; ++j) {
        int p = j * 16 + l15;
        if (p < 196) {
            s_pool[(pl + 0) * 200 + p] = fmaxf(acc[j][0] + b4.x, 0.f);
            s_pool[(pl + 1) * 200 + p] = fmaxf(acc[j][1] + b4.y, 0.f);
            s_pool[(pl + 2) * 200 + p] = fmaxf(acc[j][2] + b4.z, 0.f);
            s_pool[(pl + 3) * 200 + p] = fmaxf(acc[j][3] + b4.w, 0.f);
        }
    }
    __syncthreads();
    for (int i = tid; i < 64 * 49; i += 256) {
        int plx = i / 49, q = i - plx * 49;
        int py = q / 7, qx = q - py * 7;
        const float* rp = s_pool + plx * 200 + py * 28 + qx * 2;
        float m = fmaxf(fmaxf(rp[0], rp[1]), fmaxf(rp[14], rp[15]));
        int k = (pt * 64 + plx) * 49 + q;
        int kb = k >> 6, lq2 = (k >> 4) & 3, hi = (k >> 3) & 1, e = k & 7;
        actB[((((size_t)kb * 4 + lq2) * 2 + hi) * 64 + n) * 8 + e] = f2bf(m);
    }
}

// ---------------------------------------------------------------------------
// fc1 partial GEMM (round-10 staging). Block = (ks 0..97, jt 0..15), KC=512.
// ---------------------------------------------------------------------------
__global__ __launch_bounds__(256) void k_fc1p(const unsigned short* __restrict__ actB,
                                              const float* __restrict__ w,
                                              float* __restrict__ part)
{
    __shared__ unsigned short s_w[64 * 264];
    const int jt = blockIdx.x & 15, ks = blockIdx.x >> 4;
    const int tid = threadIdx.x, lane = tid & 63, wv = tid >> 6;
    const int l15 = lane & 15, lq = lane >> 4;
    const int k0 = ks * 512;

    f32x4 acc[4];
#pragma unroll
    for (int t = 0; t < 4; ++t) acc[t] = (f32x4){0.f, 0.f, 0.f, 0.f};

    float4 pf[16];

#define FC1_LOAD(ss_) do {                                                        \
    _Pragma("unroll")                                                             \
    for (int pass = 0; pass < 16; ++pass) {                                       \
        const int row_ = pass * 4 + wv;                                           \
        pf[pass] = *(const float4*)(w + (size_t)(jt * 64 + row_) * 50176 + k0     \
                                      + (ss_) * 256 + lane * 4);                  \
    } } while (0)

    FC1_LOAD(0);

    for (int ss = 0; ss < 2; ++ss) {
        __syncthreads();
#pragma unroll
        for (int pass = 0; pass < 16; ++pass) {
            const int row = pass * 4 + wv;
            uint2 v;
            v.x = pkbf(pf[pass].x, pf[pass].y);
            v.y = pkbf(pf[pass].z, pf[pass].w);
            *(uint2*)(s_w + row * 264 + lane * 4) = v;
        }
        __syncthreads();
        if (ss < 1) FC1_LOAD(1);

        const unsigned short* arow = s_w + (wv * 16 + l15) * 264;
#pragma unroll
        for (int kk = 0; kk < 8; ++kk) {
            bf16x8 a = *(const bf16x8*)(arow + kk * 32 + lq * 8);
            const int kglob = k0 + ss * 256 + kk * 32 + lq * 8;
            const int kb = kglob >> 6, lq2 = (kglob >> 4) & 3, hi = (kglob >> 3) & 1;
            const unsigned short* bp = actB +
                ((((size_t)kb * 4 + lq2) * 2 + hi) * 64 + l15) * 8;
#pragma unroll
            for (int t = 0; t < 4; ++t) {
                bf16x8 b = *(const bf16x8*)(bp + t * 128);
                acc[t] = mfma16(a, b, acc[t]);
            }
        }
    }
#undef FC1_LOAD

    float* pbase = part + ((size_t)ks * 1024 + jt * 64 + wv * 16 + lq * 4) * 64 + l15;
#pragma unroll
    for (int t = 0; t < 4; ++t)
#pragma unroll
        for (int r = 0; r < 4; ++r)
            pbase[(size_t)r * 64 + t * 16] = acc[t][r];
}

__global__ __launch_bounds__(256) void k_fc1r(const float* __restrict__ part,
                                              const float* __restrict__ b,
                                              float* __restrict__ fc1T)
{
    int i = blockIdx.x * 256 + threadIdx.x;
    if (i >= 65536) return;
    float s = 0.0f;
    for (int ks = 0; ks < NKS; ++ks) s += part[(size_t)ks * 65536 + i];
    int j = i >> 6;
    fc1T[i] = fmaxf(s + b[j], 0.0f);
}

__global__ __launch_bounds__(256) void k_fc2(const float* __restrict__ fc1T,
                                             const float* __restrict__ w,
                                             const float* __restrict__ b,
                                             float* __restrict__ out)
{
    __shared__ float red[256];
    const int a_ = blockIdx.x;
    const int tid = threadIdx.x, lane = tid & 63, q = tid >> 6;
    float acc = 0.0f;
    const float* wr = w + (size_t)a_ * 1024;
    for (int k = q * 256; k < q * 256 + 256; ++k)
        acc = fmaf(fc1T[k * 64 + lane], wr[k], acc);
    red[tid] = acc;
    __syncthreads();
    if (q == 0) {
        float s = red[tid] + red[tid + 64] + red[tid + 128] + red[tid + 192] + b[a_];
        out[lane * 28 + a_] = s;
    }
}

extern "C" void kernel_launch(void* const* d_in, const int* in_sizes, int n_in,
                              void* d_out, int out_size, void* d_ws, size_t ws_size,
                              hipStream_t stream)
{
    const float* feats = (const float*)d_in[0];
    const int*   prog  = (const int*)d_in[1];
    char* ws  = (char*)d_ws;
    float* out = (float*)d_out;

    // transpose feats first (independent of prep)
    k_tr<<<2048, 256, 0, stream>>>(feats, (unsigned short*)(ws + B_FT));

    PrepArgs pa;
    pa.src[0]  = (const float*)d_in[2];   // stem_w1
    pa.src[1]  = (const float*)d_in[4];   // stem_w2
    pa.src[2]  = (const float*)d_in[6];   // att_w1
    pa.src[3]  = (const float*)d_in[8];   // att_w2
    pa.src[4]  = (const float*)d_in[12];  // rel_w1
    pa.src[5]  = (const float*)d_in[14];  // rel_w2
    pa.src[6]  = (const float*)d_in[16];  // rel_w3
    pa.src[7]  = (const float*)d_in[18];  // rel_w4
    pa.src[8]  = (const float*)d_in[20];  // rel_w5
    pa.src[9]  = (const float*)d_in[24];  // qry_w1
    pa.src[10] = (const float*)d_in[26];  // qry_w2
    pa.src[11] = (const float*)d_in[28];  // cls_w
    pa.prog = prog;
    pa.ws = ws;
    k_prep<<<1024, 256, 0, stream>>>(pa);

    // stem1: FT -> partials(8) -> XA
    k_stem1p<<<512, 512, 0, stream>>>((const unsigned short*)(ws + B_FT),
                                      (const unsigned short*)(ws + B_WSTEM1), ws);
    k_stem1r<<<784, 256, 0, stream>>>(ws, (const float*)d_in[3],
                                      (unsigned short*)(ws + B_XA));

    // stem2: XA -> STEM
    k_conv_stem2<<<512, 256, 0, stream>>>((const unsigned short*)(ws + B_XA),
                                          (const unsigned short*)(ws + B_WSTEM2),
                                          (const float*)d_in[5],
                                          (unsigned short*)(ws + B_STEM));

    RArgs ga;
    ga.ws = ws;
    ga.mbias[0] = (const float*)d_in[7];   // att_b1
    ga.mbias[1] = (const float*)d_in[9];   // att_b2
    ga.mbias[2] = (const float*)d_in[13];  // rel_b1
    ga.mbias[3] = (const float*)d_in[15];  // rel_b2
    ga.mbias[4] = (const float*)d_in[17];  // rel_b3
    ga.mbias[5] = (const float*)d_in[19];  // rel_b4
    ga.mbias[6] = (const float*)d_in[21];  // rel_b5
    ga.mbias[7] = (const float*)d_in[25];  // qry_b1
    ga.mbias[8] = (const float*)d_in[27];  // qry_b2
    ga.w1x1[0]  = (const float*)d_in[10];  // att_w3
    ga.w1x1[1]  = (const float*)d_in[22];  // rel_w6
    ga.b1x1[0]  = (const float*)d_in[11];  // att_b3
    ga.b1x1[1]  = (const float*)d_in[23];  // rel_b6

    for (int r = 0; r < NROUNDS; ++r)
        k_round<<<256, 512, 0, stream>>>(ga, r);

    k_cls_pool<<<1024, 256, 0, stream>>>((const unsigned short*)(ws + B_FEAT),
                                         (const unsigned short*)(ws + B_WCLS),
                                         (const float*)d_in[29],
                                         (unsigned short*)(ws + B_ACTB));
    k_fc1p<<<1568, 256, 0, stream>>>((const unsigned short*)(ws + B_ACTB),
                                     (const float*)d_in[30], (float*)(ws + B_FC1P));
    k_fc1r<<<256, 256, 0, stream>>>((const float*)(ws + B_FC1P), (const float*)d_in[31],
                                    (float*)(ws + B_FC1T));
    k_fc2<<<28, 256, 0, stream>>>((const float*)(ws + B_FC1T), (const float*)d_in[32],
                                  (const float*)d_in[33], out);
}

// Round 15
// 488.899 us; speedup vs baseline: 1.0519x; 1.0519x over previous
//
#include <hip/hip_runtime.h>
#include <math.h>

// ---------------------------------------------------------------------------
// TbDNet forward, round 15: module-fused interpreter (4 slots), stem1r folded
// into stem2, tr folded into prep. 11 dispatches total.
// ---------------------------------------------------------------------------

typedef __attribute__((ext_vector_type(8)))  short   short8;
typedef __attribute__((ext_vector_type(8)))  __bf16  bf16x8;
typedef __attribute__((ext_vector_type(4)))  float   f32x4;

#define NSLOTS 4
#define NKS 98          // fc1 K-splits (KC = 512)
#define S1KS 8          // stem1 K-splits (128 ic each)

// byte offsets in ws
#define B_WSTEM1 0UL                 // bf16 [9][128][1024]
#define B_WSTEM2 2359296UL           // bf16 [9][128][128]
#define B_WMOD   2654208UL           // 9 x bf16 [9][128][128]
#define B_WCLS   5308416UL           // bf16 [1024][128]
#define B_STEM   5570560UL           // bf16 [64][196][128]
#define B_FEAT   15204352UL
#define B_ATTN   18415616UL          // f32 [64][196]
#define B_SAVED  18465792UL
#define B_SCHED  18515968UL          // int [64][NSLOTS]
#define B_ACTB   18520064UL          // bf16 permuted fc1-B
#define B_FC1T   24942592UL          // f32 [1024][64]
#define B_P1X1   25204736UL          // f32 [8 slots][64][196]
#define B_FT     33554432UL          // bf16 [64][196][1024]
// high overlays:
#define B_S1P    67108864UL          // stem1 partials bf16 [8][64][196][128]
#define B_FC1P   134217728UL         // fc1 partials f32 [98][1024][64]

__device__ __forceinline__ unsigned short f2bf(float f) {
    __bf16 h = (__bf16)f;
    union { __bf16 h; unsigned short u; } c; c.h = h; return c.u;
}
__device__ __forceinline__ float bf2f(unsigned short u) {
    return __uint_as_float(((unsigned int)u) << 16);
}
__device__ __forceinline__ unsigned int pkbf(float a, float b) {
    return (unsigned int)f2bf(a) | ((unsigned int)f2bf(b) << 16);
}
__device__ __forceinline__ f32x4 mfma16(bf16x8 a, bf16x8 b, f32x4 c) {
    return __builtin_amdgcn_mfma_f32_16x16x32_bf16(a, b, c, 0, 0, 0);
}

// ---------------------------------------------------------------------------
// k_prep: blocks 0..767 weight repack; 768..1023 decode+init; 1024..3071 feats
// transpose -> FT bf16 [n][196][1024].
// Module entry bits: op(2b: 0 nop, 1 FILT, 2 RELATE, 3 QUERY) | ws1<<4 |
//   scene<<17 | inter<<18 | mslot<<19(3b) | mw<<22 | pw<<24 | pslot<<25(3b)
// ---------------------------------------------------------------------------
struct PrepArgs { const float* src[12]; const int* prog; const float* feats; char* ws; };

__global__ __launch_bounds__(256) void k_prep(PrepArgs a)
{
    char* ws = a.ws;
    const int bx = blockIdx.x;
    if (bx >= 1024) {                          // transpose part
        __shared__ float s[32 * 201];
        const int bx2 = bx - 1024;
        const int n = bx2 >> 5, it = bx2 & 31;
        const int tid = threadIdx.x, lane = tid & 63, w = tid >> 6;
        const float* src = a.feats + ((size_t)n * 1024 + it * 32) * 196;
        for (int r = w; r < 32; r += 4) {
            if (lane < 49) {
                float4 v = *(const float4*)(src + r * 196 + lane * 4);
                float* sr = s + r * 201 + lane * 4;
                sr[0] = v.x; sr[1] = v.y; sr[2] = v.z; sr[3] = v.w;
            }
        }
        __syncthreads();
        const int ic4 = (tid & 7) * 4;
        unsigned short* dst = (unsigned short*)(ws + B_FT) + (size_t)n * 200704 + it * 32 + ic4;
        for (int p = tid >> 3; p < 196; p += 32) {
            uint2 v;
            v.x = pkbf(s[(ic4 + 0) * 201 + p], s[(ic4 + 1) * 201 + p]);
            v.y = pkbf(s[(ic4 + 2) * 201 + p], s[(ic4 + 3) * 201 + p]);
            *(uint2*)(dst + (size_t)p * 1024) = v;
        }
        return;
    }
    if (bx < 768) {
        const int y = bx >> 6;
        const float* __restrict__ src = a.src[y];
        int gid = (bx & 63) * 256 + threadIdx.x;
        int gsz = 64 * 256;
        if (y == 11) {
            unsigned short* dst = (unsigned short*)(ws + B_WCLS);
            for (int i = gid; i < 131072; i += gsz) dst[i] = f2bf(src[i]);
        } else {
            const int IC = (y == 0) ? 1024 : 128;
            const int lg = (y == 0) ? 10 : 7;
            unsigned short* dst = (unsigned short*)(ws + ((y == 0) ? B_WSTEM1
                                        : (y == 1) ? B_WSTEM2
                                        : B_WMOD + (size_t)(y - 2) * 294912));
            const int total = 9 << (lg + 7);
            for (int i = gid; i < total; i += gsz) {
                int ic = i & (IC - 1);
                int oc = (i >> lg) & 127;
                int t  = i >> (lg + 7);
                dst[i] = f2bf(src[((size_t)oc * IC + ic) * 9 + t]);
            }
        }
        return;
    }
    int gid = (bx - 768) * 256 + threadIdx.x;
    int gsz = 256 * 256;
    float* attn  = (float*)(ws + B_ATTN);
    float* saved = (float*)(ws + B_SAVED);
    float* p1    = (float*)(ws + B_P1X1);
    for (int i = gid; i < 64 * 196; i += gsz) { attn[i] = 1.0f; saved[i] = 1.0f; }
    for (int i = gid; i < 8 * 64 * 196; i += gsz) p1[i] = 0.0f;
    unsigned int* fz = (unsigned int*)(ws + B_FEAT);
    for (int i = gid; i < 64 * 25088 / 2; i += gsz) fz[i] = 0u;
    if (gid < 64) {
        int n = gid;
        const int* prog = a.prog;
        int ent[NSLOTS];
        for (int r = 0; r < NSLOTS; ++r) ent[r] = 0;
        int rc = 0, nslot = 0;
        int pscene = 0, pinter = 0, pmat = 0, pmw = 0;
#define PREBITS ((pscene<<17)|(pinter<<18)|(pmat<<19)|(pmw<<22))
#define CLRPRE  (pscene = pinter = pmat = pmw = 0)
#define EMIT(v) do { if (rc < NSLOTS) ent[rc++] = (v); } while (0)
        for (int j = 7; j >= 0; --j) {
            int t = prog[n * 8 + j];
            switch (t) {
                case 3: pscene = 1; break;               // SCENE
                case 4: pinter = 1; break;               // INTERSECT
                case 5: {                                 // FILT
                    int e1 = 1 | (0 << 4) | PREBITS | (0 << 24) | (nslot << 25);
                    CLRPRE; EMIT(e1);
                    pmat = nslot + 1; pmw = 0; nslot++;
                    break;
                }
                case 6: {                                 // RELATE
                    int e1 = 2 | (2 << 4) | PREBITS | (1 << 24) | (nslot << 25);
                    CLRPRE; EMIT(e1);
                    pmat = nslot + 1; pmw = 1; nslot++;
                    break;
                }
                case 7: {                                 // QUERY
                    int e1 = 3 | (7 << 4) | PREBITS;
                    CLRPRE; EMIT(e1);
                    break;
                }
                default: break;
            }
        }
#undef EMIT
#undef PREBITS
#undef CLRPRE
        int* sched = (int*)(ws + B_SCHED);
        for (int r = 0; r < NSLOTS; ++r) sched[n * NSLOTS + r] = ent[r];
    }
}

// ---------------------------------------------------------------------------
// stem1 partial conv (r14 version): block = (n, ks 0..7), 512 thr, FT source.
// ---------------------------------------------------------------------------
__global__ __launch_bounds__(512) void k_stem1p(const unsigned short* __restrict__ ft,
                                                const unsigned short* __restrict__ wrep,
                                                char* ws)
{
    __shared__ unsigned short s_img[197 * 136];
    const int bx = blockIdx.x;
    const int n = bx >> 3, ks = bx & 7;
    const int tid = threadIdx.x, lane = tid & 63;
    const int w = tid >> 6, wm = w & 1, wn = w >> 1;
    const int l15 = lane & 15, lq = lane >> 4;
    const int icb = ks * 128;

    if (tid < 68) ((unsigned int*)s_img)[196 * 68 + tid] = 0u;

    const unsigned short* slab = ft + (size_t)n * 200704 + icb;
    for (int i = tid; i < 196 * 16; i += 512) {
        int p = i >> 4, c8 = (i & 15) * 8;
        *(short8*)(s_img + p * 136 + c8) = *(const short8*)(slab + (size_t)p * 1024 + c8);
    }

    int pglob[4], pbyt[4], pyv[4], pxv[4];
#pragma unroll
    for (int j = 0; j < 4; ++j) {
        int p  = (wn + 4 * j) * 16 + l15;
        pglob[j] = p;
        int py = p / 14;
        pyv[j] = (p < 196) ? py : 10000;
        pxv[j] = p - py * 14;
        pbyt[j] = p * 272 + lq * 16;
    }
    const int zaddr = 196 * 272 + lq * 16;
    const int nJ = (wn == 0) ? 4 : 3;

    f32x4 acc[4][4];
#pragma unroll
    for (int m = 0; m < 4; ++m)
#pragma unroll
        for (int j = 0; j < 4; ++j) acc[m][j] = (f32x4){0.f, 0.f, 0.f, 0.f};
    __syncthreads();

#pragma unroll
    for (int t = 0; t < 9; ++t) {
        const int dy = t / 3 - 1, dx = t % 3 - 1;
        int baddr[4];
#pragma unroll
        for (int j = 0; j < 4; ++j) {
            int yy = pyv[j] + dy, xx = pxv[j] + dx;
            bool ok = ((unsigned)yy < 14u) && ((unsigned)xx < 14u);
            baddr[j] = ok ? (pbyt[j] + (dy * 14 + dx) * 272) : zaddr;
        }
#pragma unroll
        for (int kc = 0; kc < 4; ++kc) {
            const unsigned short* wt = wrep +
                ((size_t)(t * 128 + wm * 64 + l15) * 1024 + icb + kc * 32 + lq * 8);
            bf16x8 am[4];
#pragma unroll
            for (int m = 0; m < 4; ++m)
                am[m] = *(const bf16x8*)(wt + (size_t)m * 16 * 1024);
#pragma unroll
            for (int j = 0; j < 4; ++j) {
                if (j < nJ) {
                    bf16x8 b = *(const bf16x8*)((const char*)s_img + baddr[j] + kc * 64);
#pragma unroll
                    for (int m = 0; m < 4; ++m)
                        acc[m][j] = mfma16(am[m], b, acc[m][j]);
                }
            }
        }
    }

    unsigned short* part = (unsigned short*)(ws + B_S1P);
#pragma unroll
    for (int m = 0; m < 4; ++m) {
        const int oc = wm * 64 + m * 16 + lq * 4;
#pragma unroll
        for (int j = 0; j < 4; ++j) {
            if (j < nJ) {
                int p = pglob[j];
                if (p < 196) {
                    uint2 pk;
                    pk.x = pkbf(acc[m][j][0], acc[m][j][1]);
                    pk.y = pkbf(acc[m][j][2], acc[m][j][3]);
                    *(uint2*)(part + (((size_t)ks * 64 + n) * 196 + p) * 128 + oc) = pk;
                }
            }
        }
    }
}

// ---------------------------------------------------------------------------
// k_stem2f: stem1-reduce (inline stage) + stem2 conv. Block=(n,oct), 512 thr.
// Stage: sum 8 partial slabs + stem1 bias + relu -> bf16 s_img.
// Conv: wave w: wo=w&1 (16-oc of the oct's 32), wn=w>>1 (px interleave).
// ---------------------------------------------------------------------------
__global__ __launch_bounds__(512) void k_stem2f(char* ws,
                                                const float* __restrict__ bias1,
                                                const unsigned short* __restrict__ wrep,
                                                const float* __restrict__ bias2,
                                                unsigned short* __restrict__ stem)
{
    __shared__ unsigned short s_img[197 * 136];
    const int n = blockIdx.x >> 2, oct = blockIdx.x & 3;
    const int tid = threadIdx.x, lane = tid & 63;
    const int w = tid >> 6, wo = w & 1, wn = w >> 1;
    const int l15 = lane & 15, lq = lane >> 4;

    if (tid < 68) ((unsigned int*)s_img)[196 * 68 + tid] = 0u;

    const unsigned short* part = (const unsigned short*)(ws + B_S1P);
    for (int i = tid; i < 196 * 16; i += 512) {
        int p = i >> 4, c8 = (i & 15) * 8;
        float s[8] = {};
#pragma unroll
        for (int ks = 0; ks < S1KS; ++ks) {
            short8 v = *(const short8*)(part + (((size_t)ks * 64 + n) * 196 + p) * 128 + c8);
#pragma unroll
            for (int e = 0; e < 8; ++e) s[e] += bf2f((unsigned short)v[e]);
        }
        short8 o;
#pragma unroll
        for (int e = 0; e < 8; ++e)
            o[e] = (short)f2bf(fmaxf(s[e] + bias1[c8 + e], 0.f));
        *(short8*)(s_img + p * 136 + c8) = o;
    }
    __syncthreads();

    int pglob[4], pbyt[4], pyv[4], pxv[4];
#pragma unroll
    for (int j = 0; j < 4; ++j) {
        int p  = (wn + 4 * j) * 16 + l15;
        pglob[j] = p;
        int py = p / 14;
        pyv[j] = (p < 196) ? py : 10000;
        pxv[j] = p - py * 14;
        pbyt[j] = p * 272 + lq * 16;
    }
    const int zaddr = 196 * 272 + lq * 16;

    f32x4 acc[4];
#pragma unroll
    for (int j = 0; j < 4; ++j) acc[j] = (f32x4){0.f, 0.f, 0.f, 0.f};

    const unsigned short* wlane = wrep + (size_t)(oct * 32 + wo * 16 + l15) * 128 + lq * 8;
#pragma unroll
    for (int t = 0; t < 9; ++t) {
        const int dy = t / 3 - 1, dx = t % 3 - 1;
        int ba[4];
#pragma unroll
        for (int j = 0; j < 4; ++j) {
            int yy = pyv[j] + dy, xx = pxv[j] + dx;
            bool ok = ((unsigned)yy < 14u) && ((unsigned)xx < 14u);
            ba[j] = ok ? (pbyt[j] + (dy * 14 + dx) * 272) : zaddr;
        }
        const unsigned short* wt = wlane + (size_t)(t * 128) * 128;
#pragma unroll
        for (int kc = 0; kc < 4; ++kc) {
            bf16x8 a0 = *(const bf16x8*)(wt + kc * 32);
#pragma unroll
            for (int j = 0; j < 4; ++j) {
                bf16x8 b = *(const bf16x8*)((const char*)s_img + ba[j] + kc * 64);
                acc[j] = mfma16(a0, b, acc[j]);
            }
        }
    }

    const int oc = oct * 32 + wo * 16 + lq * 4;
    const float4 b4 = *(const float4*)(bias2 + oc);
    unsigned short* dst = stem + (size_t)n * 25088;
#pragma unroll
    for (int j = 0; j < 4; ++j) {
        int p = pglob[j];
        if (p < 196) {
            uint2 pk;
            pk.x = pkbf(fmaxf(acc[j][0] + b4.x, 0.f), fmaxf(acc[j][1] + b4.y, 0.f));
            pk.y = pkbf(fmaxf(acc[j][2] + b4.z, 0.f), fmaxf(acc[j][3] + b4.w, 0.f));
            *(uint2*)(dst + p * 128 + oc) = pk;
        }
    }
}

// ---------------------------------------------------------------------------
// k_mod: one full module per block. Grid 128 = (n, half). F/R: half0 only,
// full 128-oc chain in s_img (reg-carry across barriers), final feeds postsum
// only. Q: both halves compute; each writes its 64-oc half of FEAT.
// ---------------------------------------------------------------------------
struct RArgs {
    char* ws;
    const float* mbias[9];
    const float* w1x1[2];
    const float* b1x1[2];
};

__global__ __launch_bounds__(512) void k_mod(RArgs a, int r)
{
    __shared__ unsigned short s_img[197 * 136];
    __shared__ float s_gate[196];
    __shared__ float s_post[196];
    const int bx = blockIdx.x;
    const int n = bx >> 1, half = bx & 1;
    char* ws = a.ws;
    const int* sched = (const int*)(ws + B_SCHED);
    const int e = sched[n * NSLOTS + r];
    const int op = e & 3;
    if (op == 0) return;
    if (op != 3 && half) return;

    const int tid = threadIdx.x, lane = tid & 63, w = tid >> 6;
    const int l15 = lane & 15, lq = lane >> 4;
    const int ws1 = (e >> 4) & 15;
    const int fscene = (e >> 17) & 1, finter = (e >> 18) & 1;
    const int mslot = (e >> 19) & 7, mw = (e >> 22) & 1;
    const int pw = (e >> 24) & 1, pslot = (e >> 25) & 7;

    float* attn  = (float*)(ws + B_ATTN)  + n * 196;
    float* saved = (float*)(ws + B_SAVED) + n * 196;
    float* p1    = (float*)(ws + B_P1X1);

    if (tid < 68) ((unsigned int*)s_img)[196 * 68 + tid] = 0u;
    if (tid < 196) {
        s_post[tid] = 0.f;
        float cur = attn[tid];
        if (mslot) {
            float pv = p1[(size_t)(mslot - 1) * 12544 + n * 196 + tid];
            cur = 1.0f / (1.0f + __expf(-(pv + a.b1x1[mw][0])));
        }
        if (fscene) { saved[tid] = cur; cur = 1.0f; }
        if (finter) { cur = fminf(cur, saved[tid]); }
        if (mslot | fscene | finter) attn[tid] = cur;
        s_gate[tid] = cur;
    }
    __syncthreads();

    // stage gated STEM
    const unsigned short* stem = (const unsigned short*)(ws + B_STEM) + (size_t)n * 25088;
    for (int i = tid; i < 196 * 16; i += 512) {
        int p = i >> 4, c8 = (i & 15) * 8;
        short8 v = *(const short8*)(stem + p * 128 + c8);
        float g = s_gate[p];
        uint2 o0, o1;
        o0.x = pkbf(bf2f((unsigned short)v[0]) * g, bf2f((unsigned short)v[1]) * g);
        o0.y = pkbf(bf2f((unsigned short)v[2]) * g, bf2f((unsigned short)v[3]) * g);
        o1.x = pkbf(bf2f((unsigned short)v[4]) * g, bf2f((unsigned short)v[5]) * g);
        o1.y = pkbf(bf2f((unsigned short)v[6]) * g, bf2f((unsigned short)v[7]) * g);
        *(uint2*)(s_img + p * 136 + c8)     = o0;
        *(uint2*)(s_img + p * 136 + c8 + 4) = o1;
    }

    const unsigned short* wmod = (const unsigned short*)(ws + B_WMOD);
    const int zaddr = 196 * 272 + lq * 16;
    const int nconv = (op == 2) ? 5 : 2;

    int pg2[13], pb2[13], pyv2[13], pxv2[13];
#pragma unroll
    for (int j2 = 0; j2 < 13; ++j2) {
        int p = j2 * 16 + l15;
        pg2[j2] = p;
        int py = p / 14;
        pyv2[j2] = (p < 196) ? py : 10000;
        pxv2[j2] = p - py * 14;
        pb2[j2] = p * 272 + lq * 16;
    }

    for (int c = 0; c < nconv; ++c) {
        __syncthreads();                       // stage or prev writes visible
        const int dil = (op == 2) ? ((c == 1) ? 2 : (c == 2) ? 4 : (c == 3) ? 8 : 1) : 1;
        const unsigned short* wt0 = wmod + (size_t)(ws1 + c) * 147456;

        f32x4 acc1[13];
#pragma unroll
        for (int j2 = 0; j2 < 13; ++j2) acc1[j2] = (f32x4){0.f, 0.f, 0.f, 0.f};

#pragma unroll
        for (int t = 0; t < 9; ++t) {
            const int dy = (t / 3 - 1) * dil, dx = (t % 3 - 1) * dil;
            int ba[13];
#pragma unroll
            for (int j2 = 0; j2 < 13; ++j2) {
                int yy = pyv2[j2] + dy, xx = pxv2[j2] + dx;
                bool ok = ((unsigned)yy < 14u) && ((unsigned)xx < 14u);
                ba[j2] = ok ? (pb2[j2] + (dy * 14 + dx) * 272) : zaddr;
            }
#pragma unroll
            for (int kc = 0; kc < 4; ++kc) {
                bf16x8 av = *(const bf16x8*)(wt0 +
                    (size_t)(t * 128 + w * 16 + l15) * 128 + kc * 32 + lq * 8);
#pragma unroll
                for (int j2 = 0; j2 < 13; ++j2) {
                    bf16x8 b = *(const bf16x8*)((const char*)s_img + ba[j2] + kc * 64);
                    acc1[j2] = mfma16(av, b, acc1[j2]);
                }
            }
        }
        __syncthreads();                       // all reads of s_img done

        const int oc1 = w * 16 + lq * 4;
        const float4 b4 = *(const float4*)(a.mbias[ws1 + c] + oc1);

        if (c < nconv - 1) {
            // mid conv: relu -> bf16 -> s_img (overwrite)
#pragma unroll
            for (int j2 = 0; j2 < 13; ++j2) {
                int p = pg2[j2];
                if (p < 196) {
                    uint2 pk;
                    pk.x = pkbf(fmaxf(acc1[j2][0] + b4.x, 0.f),
                                fmaxf(acc1[j2][1] + b4.y, 0.f));
                    pk.y = pkbf(fmaxf(acc1[j2][2] + b4.z, 0.f),
                                fmaxf(acc1[j2][3] + b4.w, 0.f));
                    *(uint2*)(s_img + p * 136 + oc1) = pk;
                }
            }
        } else if (op == 3) {
            // QUERY final: write own 64-oc half of FEAT
            if ((w >> 2) == half) {
                unsigned short* feat = (unsigned short*)(ws + B_FEAT) + (size_t)n * 25088;
#pragma unroll
                for (int j2 = 0; j2 < 13; ++j2) {
                    int p = pg2[j2];
                    if (p < 196) {
                        uint2 pk;
                        pk.x = pkbf(fmaxf(acc1[j2][0] + b4.x, 0.f),
                                    fmaxf(acc1[j2][1] + b4.y, 0.f));
                        pk.y = pkbf(fmaxf(acc1[j2][2] + b4.z, 0.f),
                                    fmaxf(acc1[j2][3] + b4.w, 0.f));
                        *(uint2*)(feat + p * 128 + oc1) = pk;
                    }
                }
            }
        } else {
            // FILT/RELATE final: postsum (1x1 weights) into s_post then p1
            const float4 wv4 = *(const float4*)(a.w1x1[pw] + oc1);
#pragma unroll
            for (int j2 = 0; j2 < 13; ++j2) {
                int p = pg2[j2];
                float v0 = fmaxf(acc1[j2][0] + b4.x, 0.f);
                float v1 = fmaxf(acc1[j2][1] + b4.y, 0.f);
                float v2 = fmaxf(acc1[j2][2] + b4.z, 0.f);
                float v3 = fmaxf(acc1[j2][3] + b4.w, 0.f);
                float s = v0 * wv4.x + v1 * wv4.y + v2 * wv4.z + v3 * wv4.w;
                s += __shfl_xor(s, 16);
                s += __shfl_xor(s, 32);
                if (lq == 0 && p < 196) atomicAdd(&s_post[p], s);
            }
            __syncthreads();
            if (tid < 196)
                p1[(size_t)pslot * 12544 + n * 196 + tid] = s_post[tid];
        }
    }
}

// ---------------------------------------------------------------------------
// cls 1x1 conv (128->1024, MFMA) + bias + relu + 2x2 maxpool -> actB bf16
// ---------------------------------------------------------------------------
__global__ __launch_bounds__(256) void k_cls_pool(const unsigned short* __restrict__ featall,
                                                  const unsigned short* __restrict__ clsw,
                                                  const float* __restrict__ clsb,
                                                  unsigned short* __restrict__ actB)
{
    __shared__ char smem[197 * 272 + 64 * 200 * 4];
    unsigned short* s_img = (unsigned short*)smem;
    float* s_pool = (float*)(smem + 197 * 272);
    const int n = blockIdx.x >> 4, pt = blockIdx.x & 15;
    const int tid = threadIdx.x, lane = tid & 63, w = tid >> 6;
    const int l15 = lane & 15, lq = lane >> 4;
    const unsigned short* feat = featall + (size_t)n * 25088;

    if (tid < 68) ((unsigned int*)s_img)[196 * 68 + tid] = 0u;
    for (int i = tid; i < 196 * 16; i += 256) {
        int p = i >> 4, c8 = (i & 15) * 8;
        *(short8*)(s_img + p * 136 + c8) = *(const short8*)(feat + p * 128 + c8);
    }
    f32x4 acc[14];
#pragma unroll
    for (int j = 0; j < 14; ++j) acc[j] = (f32x4){0.f, 0.f, 0.f, 0.f};
    __syncthreads();

    const unsigned short* wl = clsw + (size_t)(pt * 64 + w * 16 + l15) * 128 + lq * 8;
#pragma unroll
    for (int kc = 0; kc < 4; ++kc) {
        bf16x8 a0 = *(const bf16x8*)(wl + kc * 32);
#pragma unroll
        for (int j = 0; j < 14; ++j) {
            int p = j * 16 + l15;
            int ba = (p < 196) ? (p * 272 + lq * 16 + kc * 64) : (196 * 272 + lq * 16);
            bf16x8 b = *(const bf16x8*)((const char*)s_img + ba);
            acc[j] = mfma16(a0, b, acc[j]);
        }
    }
    const int oc = pt * 64 + w * 16 + lq * 4;
    const float4 b4 = *(const float4*)(clsb + oc);
    const int pl = w * 16 + lq * 4;
#pragma unroll
    for (int j = 0; j < 14; ++j) {
        int p = j * 16 + l15;
        if (p < 196) {
            s_pool[(pl + 0) * 200 + p] = fmaxf(acc[j][0] + b4.x, 0.f);
            s_pool[(pl + 1) * 200 + p] = fmaxf(acc[j][1] + b4.y, 0.f);
            s_pool[(pl + 2) * 200 + p] = fmaxf(acc[j][2] + b4.z, 0.f);
            s_pool[(pl + 3) * 200 + p] = fmaxf(acc[j][3] + b4.w, 0.f);
        }
    }
    __syncthreads();
    for (int i = tid; i < 64 * 49; i += 256) {
        int plx = i / 49, q = i - plx * 49;
        int py = q / 7, qx = q - py * 7;
        const float* rp = s_pool + plx * 200 + py * 28 + qx * 2;
        float m = fmaxf(fmaxf(rp[0], rp[1]), fmaxf(rp[14], rp[15]));
        int k = (pt * 64 + plx) * 49 + q;
        int kb = k >> 6, lq2 = (k >> 4) & 3, hi = (k >> 3) & 1, e2 = k & 7;
        actB[((((size_t)kb * 4 + lq2) * 2 + hi) * 64 + n) * 8 + e2] = f2bf(m);
    }
}

// ---------------------------------------------------------------------------
// fc1 partial GEMM (round-10 staging). Block = (ks 0..97, jt 0..15), KC=512.
// ---------------------------------------------------------------------------
__global__ __launch_bounds__(256) void k_fc1p(const unsigned short* __restrict__ actB,
                                              const float* __restrict__ w,
                                              float* __restrict__ part)
{
    __shared__ unsigned short s_w[64 * 264];
    const int jt = blockIdx.x & 15, ks = blockIdx.x >> 4;
    const int tid = threadIdx.x, lane = tid & 63, wv = tid >> 6;
    const int l15 = lane & 15, lq = lane >> 4;
    const int k0 = ks * 512;

    f32x4 acc[4];
#pragma unroll
    for (int t = 0; t < 4; ++t) acc[t] = (f32x4){0.f, 0.f, 0.f, 0.f};

    float4 pf[16];

#define FC1_LOAD(ss_) do {                                                        \
    _Pragma("unroll")                                                             \
    for (int pass = 0; pass < 16; ++pass) {                                       \
        const int row_ = pass * 4 + wv;                                           \
        pf[pass] = *(const float4*)(w + (size_t)(jt * 64 + row_) * 50176 + k0     \
                                      + (ss_) * 256 + lane * 4);                  \
    } } while (0)

    FC1_LOAD(0);

    for (int ss = 0; ss < 2; ++ss) {
        __syncthreads();
#pragma unroll
        for (int pass = 0; pass < 16; ++pass) {
            const int row = pass * 4 + wv;
            uint2 v;
            v.x = pkbf(pf[pass].x, pf[pass].y);
            v.y = pkbf(pf[pass].z, pf[pass].w);
            *(uint2*)(s_w + row * 264 + lane * 4) = v;
        }
        __syncthreads();
        if (ss < 1) FC1_LOAD(1);

        const unsigned short* arow = s_w + (wv * 16 + l15) * 264;
#pragma unroll
        for (int kk = 0; kk < 8; ++kk) {
            bf16x8 a = *(const bf16x8*)(arow + kk * 32 + lq * 8);
            const int kglob = k0 + ss * 256 + kk * 32 + lq * 8;
            const int kb = kglob >> 6, lq2 = (kglob >> 4) & 3, hi = (kglob >> 3) & 1;
            const unsigned short* bp = actB +
                ((((size_t)kb * 4 + lq2) * 2 + hi) * 64 + l15) * 8;
#pragma unroll
            for (int t = 0; t < 4; ++t) {
                bf16x8 b = *(const bf16x8*)(bp + t * 128);
                acc[t] = mfma16(a, b, acc[t]);
            }
        }
    }
#undef FC1_LOAD

    float* pbase = part + ((size_t)ks * 1024 + jt * 64 + wv * 16 + lq * 4) * 64 + l15;
#pragma unroll
    for (int t = 0; t < 4; ++t)
#pragma unroll
        for (int r2 = 0; r2 < 4; ++r2)
            pbase[(size_t)r2 * 64 + t * 16] = acc[t][r2];
}

__global__ __launch_bounds__(256) void k_fc1r(const float* __restrict__ part,
                                              const float* __restrict__ b,
                                              float* __restrict__ fc1T)
{
    int i = blockIdx.x * 256 + threadIdx.x;
    if (i >= 65536) return;
    float s = 0.0f;
    for (int ks = 0; ks < NKS; ++ks) s += part[(size_t)ks * 65536 + i];
    int j = i >> 6;
    fc1T[i] = fmaxf(s + b[j], 0.0f);
}

__global__ __launch_bounds__(256) void k_fc2(const float* __restrict__ fc1T,
                                             const float* __restrict__ w,
                                             const float* __restrict__ b,
                                             float* __restrict__ out)
{
    __shared__ float red[256];
    const int a_ = blockIdx.x;
    const int tid = threadIdx.x, lane = tid & 63, q = tid >> 6;
    float acc = 0.0f;
    const float* wr = w + (size_t)a_ * 1024;
    for (int k = q * 256; k < q * 256 + 256; ++k)
        acc = fmaf(fc1T[k * 64 + lane], wr[k], acc);
    red[tid] = acc;
    __syncthreads();
    if (q == 0) {
        float s = red[tid] + red[tid + 64] + red[tid + 128] + red[tid + 192] + b[a_];
        out[lane * 28 + a_] = s;
    }
}

extern "C" void kernel_launch(void* const* d_in, const int* in_sizes, int n_in,
                              void* d_out, int out_size, void* d_ws, size_t ws_size,
                              hipStream_t stream)
{
    const float* feats = (const float*)d_in[0];
    const int*   prog  = (const int*)d_in[1];
    char* ws  = (char*)d_ws;
    float* out = (float*)d_out;

    PrepArgs pa;
    pa.src[0]  = (const float*)d_in[2];   // stem_w1
    pa.src[1]  = (const float*)d_in[4];   // stem_w2
    pa.src[2]  = (const float*)d_in[6];   // att_w1
    pa.src[3]  = (const float*)d_in[8];   // att_w2
    pa.src[4]  = (const float*)d_in[12];  // rel_w1
    pa.src[5]  = (const float*)d_in[14];  // rel_w2
    pa.src[6]  = (const float*)d_in[16];  // rel_w3
    pa.src[7]  = (const float*)d_in[18];  // rel_w4
    pa.src[8]  = (const float*)d_in[20];  // rel_w5
    pa.src[9]  = (const float*)d_in[24];  // qry_w1
    pa.src[10] = (const float*)d_in[26];  // qry_w2
    pa.src[11] = (const float*)d_in[28];  // cls_w
    pa.prog = prog;
    pa.feats = feats;
    pa.ws = ws;
    k_prep<<<3072, 256, 0, stream>>>(pa);

    k_stem1p<<<512, 512, 0, stream>>>((const unsigned short*)(ws + B_FT),
                                      (const unsigned short*)(ws + B_WSTEM1), ws);

    k_stem2f<<<256, 512, 0, stream>>>(ws, (const float*)d_in[3],
                                      (const unsigned short*)(ws + B_WSTEM2),
                                      (const float*)d_in[5],
                                      (unsigned short*)(ws + B_STEM));

    RArgs ga;
    ga.ws = ws;
    ga.mbias[0] = (const float*)d_in[7];   // att_b1
    ga.mbias[1] = (const float*)d_in[9];   // att_b2
    ga.mbias[2] = (const float*)d_in[13];  // rel_b1
    ga.mbias[3] = (const float*)d_in[15];  // rel_b2
    ga.mbias[4] = (const float*)d_in[17];  // rel_b3
    ga.mbias[5] = (const float*)d_in[19];  // rel_b4
    ga.mbias[6] = (const float*)d_in[21];  // rel_b5
    ga.mbias[7] = (const float*)d_in[25];  // qry_b1
    ga.mbias[8] = (const float*)d_in[27];  // qry_b2
    ga.w1x1[0]  = (const float*)d_in[10];  // att_w3
    ga.w1x1[1]  = (const float*)d_in[22];  // rel_w6
    ga.b1x1[0]  = (const float*)d_in[11];  // att_b3
    ga.b1x1[1]  = (const float*)d_in[23];  // rel_b6

    for (int r = 0; r < NSLOTS; ++r)
        k_mod<<<128, 512, 0, stream>>>(ga, r);

    k_cls_pool<<<1024, 256, 0, stream>>>((const unsigned short*)(ws + B_FEAT),
                                         (const unsigned short*)(ws + B_WCLS),
                                         (const float*)d_in[29],
                                         (unsigned short*)(ws + B_ACTB));
    k_fc1p<<<1568, 256, 0, stream>>>((const unsigned short*)(ws + B_ACTB),
                                     (const float*)d_in[30], (float*)(ws + B_FC1P));
    k_fc1r<<<256, 256, 0, stream>>>((const float*)(ws + B_FC1P), (const float*)d_in[31],
                                    (float*)(ws + B_FC1T));
    k_fc2<<<28, 256, 0, stream>>>((const float*)(ws + B_FC1T), (const float*)d_in[32],
                                  (const float*)d_in[33], out);
}